// Round 16
// baseline (676.961 us; speedup 1.0000x reference)
//
#include <hip/hip_runtime.h>
#include <hip/hip_bf16.h>
#include <stdint.h>

typedef __bf16 bf16x8 __attribute__((ext_vector_type(8)));
typedef float f32x4 __attribute__((ext_vector_type(4)));

// ---- helpers ------------------------------------------------------------

__device__ inline void gload_lds16(const void* g, void* lds) {
  __builtin_amdgcn_global_load_lds(
      (const __attribute__((address_space(1))) uint32_t*)(uintptr_t)g,
      (__attribute__((address_space(3))) uint32_t*)(uintptr_t)lds,
      16, 0, 0);
}

// Ordered LDS vector read (issue order preserved; lgkm counted exact).
__device__ inline bf16x8 ds_readv(uint32_t addr) {
  bf16x8 r;
  asm volatile("ds_read_b128 %0, %1" : "=v"(r) : "v"(addr));
  return r;
}

// B fragment load, saddr form: 32-bit per-lane voffset + SGPR base.
#define GLBS(dst, voff, base, OFF)                                   \
  asm volatile("global_load_dwordx4 %0, %1, %2 offset:" #OFF         \
               : "=v"(dst) : "v"(voff), "s"(base))

#define LGKM(N) do {                                             \
    asm volatile("s_waitcnt lgkmcnt(" #N ")" ::: "memory");      \
    __builtin_amdgcn_sched_barrier(0);                           \
  } while (0)
#define VM(N) do {                                               \
    asm volatile("s_waitcnt vmcnt(" #N ")" ::: "memory");        \
    __builtin_amdgcn_sched_barrier(0);                           \
  } while (0)

__device__ inline short f2bf(float f) {
  union { float f; uint32_t u; } x; x.f = f;
  uint32_t u = x.u;
  u += 0x7fffu + ((u >> 16) & 1u);   // RNE
  return (short)(u >> 16);
}

#define BAR() do { asm volatile("" ::: "memory"); \
                   __builtin_amdgcn_s_barrier();  \
                   asm volatile("" ::: "memory"); } while (0)

// ---- fp32 -> bf16 convert (vectorized) ----------------------------------

__global__ __launch_bounds__(256) void cvt_f32_bf16(
    const float* __restrict__ in, short* __restrict__ out, int n4) {
  int i = blockIdx.x * 256 + threadIdx.x;
  if (i < n4) {
    float4 v = reinterpret_cast<const float4*>(in)[i];
    short4 o;
    o.x = f2bf(v.x); o.y = f2bf(v.y); o.z = f2bf(v.z); o.w = f2bf(v.w);
    reinterpret_cast<short4*>(out)[i] = o;
  }
}

// ---- GEMM: C[M,N] = A[M,K] @ B[N,K]^T, bf16 in, fp32 acc ---------------
// B-DIRECT, SINGLE-BUFFERED (r14 fix): B frags global->regs, ONE bq set
// (r14's spill was the double X/Y sets). bq(t+1) is loaded after Q4(t)
// consumes bq(t) (register WAR, compiler-ordered + sched_barrier) and
// has a full tile (~3000 cyc >> L2 latency) to land. A stays in LDS
// double-buffer (r8 path). DS reads 24->16/wave/tile; 1 barrier + 2
// counted VMs per tile; LDS 64 KiB. VGPR ~ 128 acc + 64 Afrag + 32 B
// + ~20 addr = 244 < 256.
//
// 256x256 tile, BK=64, 8 waves (2Mx4N), per-wave 128x64 = acc[8][4] of
// mfma_f32_16x16x32_bf16 (swapped operands; values/mapping verified
// r5-r15; B-direct values verified r14 which PASSED).
// LDS (A only): 2 buf x 2 slots x [128x64] bf16 = 64 KiB;
//   A0=+0 (m0-3), A1=+16384 (m4-7); buf1=+32768. Swizzle
//   addr = slotrow*128 + ((kk*4+kq)^(fr&7))*16 (0-conflict, r2-r15).
// B frags: bq[n][kk] <- B[bcol*256+wc*64+n*16+fr][kt*64+kk*32+kq*8];
//   voff[n] = (row*K + kq*8)*2 bytes (max 134MB < 2^31), kk via
//   offset:0/64; advance +128 bytes per tile.
//
// Per tile t (cur=t&1, cb=cur*32768, nxt=cur^1; bq(t) in flight on
// entry; A(t) published by BAR(t-1)):
//   RD_A0(cb) RD_A1(cb)       // 16 ds; a1q drains under Q1/Q2
//   [s1] STAGE A0(t+1)->nxt   // 2 gl
//   [s1] VM(2) | else VM(0)   // bq(t) landed (regs private, no BAR)
//   LGKM(8)                   // a0q ready
//   prio Q1 Q2 (32 MFMA, a0q x bq)
//   [s1] STAGE A1(t+1)->nxt   // 2 gl
//   LGKM(0)                   // a1q ready
//   prio Q3 Q4 (32 MFMA, a1q x bq)
//   sched_barrier; [s1] BFRAG(t+1)   // 8 gl, overwrites bq AFTER Q4
//   [s1] VM(8); BAR           // A stages landed; publish A(t+1)
// VM ledger (steady): enter t with bq(t)[8]; +stageA0(2)=10, VM(2)
//   leaves stageA0, retires bq(t) ✓; +stageA1(2)+BFRAG(8)=12, VM(8)
//   leaves bq(t+1), retires both A stages before BAR ✓.
// Clobber: stage into buf[nxt]; all reads of buf[nxt] (tile t-1)
//   LGKM-completed before BAR(t-1); stages issue after BAR(t-1) ✓.
// Prologue: STAGE A0(0),A1(0); BFRAG(0); VM(8) retires A(0); BAR.
// Tail t=nk-1: no stages/BFRAG; VM(0); no end BAR.
// Epilogue (verified r5-r15): lane&15=M-row, 4 acc regs = 4 consecutive
// N-cols. EPI=0: bias+relu^2->bf16 (short4); EPI=1: bias->f32 (float4).

template <int EPI>
__global__ __launch_bounds__(512, 2) void gemm_bt(
    const short* __restrict__ A, const short* __restrict__ B,
    const float* __restrict__ bias, void* __restrict__ Cout,
    int M, int N, int K) {
  __shared__ __align__(16) short lds[2][2][128 * 64];   // 64 KiB, A only

  const int tid  = threadIdx.x;
  const int wave = tid >> 6;
  const int lane = tid & 63;
  const int wr = wave >> 2;          // 0..1 -> M half (128 rows)
  const int wc = wave & 3;           // 0..3 -> N quarter (64 cols)
  const int fr = lane & 15, kq = lane >> 4;

  // T1: bijective XCD swizzle (nwg % 8 == 0), column-major in-chunk
  const int nwg = gridDim.x;
  const int w = (blockIdx.x & 7) * (nwg >> 3) + (blockIdx.x >> 3);
  const int gy = M >> 8;
  const int brow = w % gy;
  const int bcol = w / gy;

  f32x4 acc[8][4];
#pragma unroll
  for (int m = 0; m < 8; ++m)
#pragma unroll
    for (int n = 0; n < 4; ++n)
      acc[m][n] = (f32x4){0.f, 0.f, 0.f, 0.f};

  const int nk = K >> 6;             // K-tiles of 64 (even; >=4)

  // ---- A fragment read addresses (buf0); buf1 = +32768 via cb
  const uint32_t LB = (uint32_t)(uintptr_t)&lds[0][0][0];
  uint32_t aA[4][2];
#pragma unroll
  for (int m = 0; m < 4; ++m)
#pragma unroll
    for (int kk = 0; kk < 2; ++kk) {
      int r = wr * 64 + m * 16 + fr;
      int g = r * 8 + kk * 4 + kq;
      aA[m][kk] = LB + (uint32_t)((g ^ (r & 7)) * 16);
    }

  // ---- A stage source addressing (inverse swizzle on global side)
  const int i0 = tid;
  const int gl0 = i0 ^ ((i0 >> 3) & 7);
  const int r0 = gl0 >> 3, c0 = gl0 & 7;
  const size_t rstep = (size_t)128 * K;

  const short* pA[2];
#pragma unroll
  for (int h = 0; h < 2; ++h)
    pA[h] = A + (size_t)(brow * 256 + h * 64 + r0) * K + c0 * 8;

  // ---- B fragment voffsets (bytes), SGPR base = B
  uint32_t vB[4];
#pragma unroll
  for (int n = 0; n < 4; ++n)
    vB[n] = (uint32_t)(((size_t)(bcol * 256 + wc * 64 + n * 16 + fr) * K
                        + kq * 8) * 2);

  const int dst0 = wave * 512, dst1 = 4096 + wave * 512;  // shorts in slot

#define STAGE(p, buf, slot)                              \
  do {                                                   \
    short* base_ = &lds[buf][slot][0];                   \
    gload_lds16((p), base_ + dst0);                      \
    gload_lds16((p) + rstep, base_ + dst1);              \
    (p) += 64;                                           \
  } while (0)

  // ---- fragment regs
  bf16x8 a0q[4][2], a1q[4][2], bq[4][2];

  auto BFRAG = [&]() {
    GLBS(bq[0][0], vB[0], B, 0);  GLBS(bq[0][1], vB[0], B, 64);
    GLBS(bq[1][0], vB[1], B, 0);  GLBS(bq[1][1], vB[1], B, 64);
    GLBS(bq[2][0], vB[2], B, 0);  GLBS(bq[2][1], vB[2], B, 64);
    GLBS(bq[3][0], vB[3], B, 0);  GLBS(bq[3][1], vB[3], B, 64);
    vB[0] += 128; vB[1] += 128; vB[2] += 128; vB[3] += 128;
  };
  auto RD_A0 = [&](uint32_t cb) {
#pragma unroll
    for (int m = 0; m < 4; ++m)
#pragma unroll
      for (int kk = 0; kk < 2; ++kk)
        a0q[m][kk] = ds_readv(aA[m][kk] + cb);
  };
  auto RD_A1 = [&](uint32_t cb) {
#pragma unroll
    for (int m = 0; m < 4; ++m)
#pragma unroll
      for (int kk = 0; kk < 2; ++kk)
        a1q[m][kk] = ds_readv(aA[m][kk] + cb + 16384u);
  };
  auto Q12 = [&]() {   // m0-3 x all n (a0q)
#pragma unroll
    for (int m = 0; m < 4; ++m)
#pragma unroll
      for (int n = 0; n < 4; ++n)
#pragma unroll
        for (int kk = 0; kk < 2; ++kk)
          acc[m][n] = __builtin_amdgcn_mfma_f32_16x16x32_bf16(
              bq[n][kk], a0q[m][kk], acc[m][n], 0, 0, 0);
  };
  auto Q34 = [&]() {   // m4-7 x all n (a1q)
#pragma unroll
    for (int m = 0; m < 4; ++m)
#pragma unroll
      for (int n = 0; n < 4; ++n)
#pragma unroll
        for (int kk = 0; kk < 2; ++kk)
          acc[m + 4][n] = __builtin_amdgcn_mfma_f32_16x16x32_bf16(
              bq[n][kk], a1q[m][kk], acc[m + 4][n], 0, 0, 0);
  };

#define PRIO_ON  __builtin_amdgcn_s_setprio(1)
#define PRIO_OFF __builtin_amdgcn_s_setprio(0)

  // ---- body: one K-tile ----
  auto body = [&](int t, uint32_t cb, int nxt) {
    const bool s1 = (t + 1) < nk;
    RD_A0(cb);
    RD_A1(cb);                                  // drains under Q12
    if (s1) STAGE(pA[0], nxt, 0);               // A0(t+1), 2 gl
    __builtin_amdgcn_sched_barrier(0);
    if (s1) { VM(2); } else { VM(0); }          // bq(t) landed
    LGKM(8);                                    // a0q ready
    PRIO_ON; Q12(); PRIO_OFF;
    if (s1) STAGE(pA[1], nxt, 1);               // A1(t+1), 2 gl
    LGKM(0);                                    // a1q ready
    PRIO_ON; Q34(); PRIO_OFF;
    __builtin_amdgcn_sched_barrier(0);          // pin BFRAG after Q34
    if (s1) {
      BFRAG();                                  // bq(t+1), 8 gl
      VM(8);                                    // A stages landed
      BAR();                                    // publish A(t+1)
    }
  };

  // ---- prologue: stage A(0), load bq(0), publish A(0).
  STAGE(pA[0], 0, 0);
  STAGE(pA[1], 0, 1);
  __builtin_amdgcn_sched_barrier(0);
  BFRAG();
  VM(8);                 // A(0) (oldest 4 of 12) landed; bq(0) in flight
  BAR();

  for (int t = 0; t < nk; t += 2) {
    body(t,     0u,     1);
    body(t + 1, 32768u, 0);
  }

  // ---- epilogue (verified r5-r15): row = m*16+fr, cols = n*16+q*4+{0..3}
  const int q = lane >> 4;
  if (EPI == 0) {
    short* C = (short*)Cout;
#pragma unroll
    for (int m = 0; m < 8; ++m) {
      const int row = brow * 256 + wr * 128 + m * 16 + fr;
#pragma unroll
      for (int n = 0; n < 4; ++n) {
        const int col = bcol * 256 + wc * 64 + n * 16 + q * 4;
        const float4 bv = *(const float4*)&bias[col];
        short4 o;
        float v0 = acc[m][n][0] + bv.x; v0 = v0 > 0.f ? v0 * v0 : 0.f;
        float v1 = acc[m][n][1] + bv.y; v1 = v1 > 0.f ? v1 * v1 : 0.f;
        float v2 = acc[m][n][2] + bv.z; v2 = v2 > 0.f ? v2 * v2 : 0.f;
        float v3 = acc[m][n][3] + bv.w; v3 = v3 > 0.f ? v3 * v3 : 0.f;
        o.x = f2bf(v0); o.y = f2bf(v1); o.z = f2bf(v2); o.w = f2bf(v3);
        *(short4*)&C[(size_t)row * N + col] = o;
      }
    }
  } else {
    float* C = (float*)Cout;
#pragma unroll
    for (int m = 0; m < 8; ++m) {
      const int row = brow * 256 + wr * 128 + m * 16 + fr;
#pragma unroll
      for (int n = 0; n < 4; ++n) {
        const int col = bcol * 256 + wc * 64 + n * 16 + q * 4;
        const float4 bv = *(const float4*)&bias[col];
        float4 o;
        o.x = acc[m][n][0] + bv.x;
        o.y = acc[m][n][1] + bv.y;
        o.z = acc[m][n][2] + bv.z;
        o.w = acc[m][n][3] + bv.w;
        *(float4*)&C[(size_t)row * N + col] = o;
      }
    }
  }
#undef STAGE
}

// ---- launch -------------------------------------------------------------

extern "C" void kernel_launch(void* const* d_in, const int* in_sizes, int n_in,
                              void* d_out, int out_size, void* d_ws,
                              size_t ws_size, hipStream_t stream) {
  const float* x  = (const float*)d_in[0];
  const float* w1 = (const float*)d_in[1];
  const float* b1 = (const float*)d_in[2];
  const float* w2 = (const float*)d_in[3];
  const float* b2 = (const float*)d_in[4];
  float* out = (float*)d_out;

  const int H = in_sizes[2];            // 8192
  const int D = in_sizes[4];            // 2048
  const int M = in_sizes[0] / D;        // B*S = 8192

  short* xb  = (short*)d_ws;                 // M*D
  short* w1b = xb  + (size_t)M * D;          // H*D
  short* w2b = w1b + (size_t)H * D;          // D*H
  short* act = w2b + (size_t)D * H;          // M*H

  {
    int n4 = (M * D) / 4;
    cvt_f32_bf16<<<(n4 + 255) / 256, 256, 0, stream>>>(x, xb, n4);
    n4 = (H * D) / 4;
    cvt_f32_bf16<<<(n4 + 255) / 256, 256, 0, stream>>>(w1, w1b, n4);
    n4 = (D * H) / 4;
    cvt_f32_bf16<<<(n4 + 255) / 256, 256, 0, stream>>>(w2, w2b, n4);
  }

  // GEMM1: [M,D] @ [H,D]^T -> sqrelu -> act[M,H] (bf16)
  gemm_bt<0><<<(M / 256) * (H / 256), 512, 0, stream>>>(
      xb, w1b, b1, (void*)act, M, H, D);
  // GEMM2: [M,H] @ [D,H]^T -> + b2 -> out[M,D] (f32)
  gemm_bt<1><<<(M / 256) * (D / 256), 512, 0, stream>>>(
      act, w2b, b2, (void*)out, M, D, H);
}

// Round 17
// 544.407 us; speedup vs baseline: 1.2435x; 1.2435x over previous
//
#include <hip/hip_runtime.h>
#include <hip/hip_bf16.h>
#include <stdint.h>

typedef __bf16 bf16x8 __attribute__((ext_vector_type(8)));
typedef float f32x4 __attribute__((ext_vector_type(4)));

// ---- helpers ------------------------------------------------------------

__device__ inline void gload_lds16(const void* g, void* lds) {
  __builtin_amdgcn_global_load_lds(
      (const __attribute__((address_space(1))) uint32_t*)(uintptr_t)g,
      (__attribute__((address_space(3))) uint32_t*)(uintptr_t)lds,
      16, 0, 0);
}

// Ordered LDS vector read (volatile asm: issue order preserved; DS
// completion in-order per wave -> counted lgkmcnt is exact).
__device__ inline bf16x8 ds_readv(uint32_t addr) {
  bf16x8 r;
  asm volatile("ds_read_b128 %0, %1" : "=v"(r) : "v"(addr));
  return r;
}

#define LGKM(N) do {                                             \
    asm volatile("s_waitcnt lgkmcnt(" #N ")" ::: "memory");      \
    __builtin_amdgcn_sched_barrier(0);                           \
  } while (0)
#define VM(N) do {                                               \
    asm volatile("s_waitcnt vmcnt(" #N ")" ::: "memory");        \
    __builtin_amdgcn_sched_barrier(0);                           \
  } while (0)

__device__ inline short f2bf(float f) {
  union { float f; uint32_t u; } x; x.f = f;
  uint32_t u = x.u;
  u += 0x7fffu + ((u >> 16) & 1u);   // RNE
  return (short)(u >> 16);
}

#define BAR() do { asm volatile("" ::: "memory"); \
                   __builtin_amdgcn_s_barrier();  \
                   asm volatile("" ::: "memory"); } while (0)

// ---- fp32 -> bf16 convert (vectorized) ----------------------------------

__global__ __launch_bounds__(256) void cvt_f32_bf16(
    const float* __restrict__ in, short* __restrict__ out, int n4) {
  int i = blockIdx.x * 256 + threadIdx.x;
  if (i < n4) {
    float4 v = reinterpret_cast<const float4*>(in)[i];
    short4 o;
    o.x = f2bf(v.x); o.y = f2bf(v.y); o.z = f2bf(v.z); o.w = f2bf(v.w);
    reinterpret_cast<short4*>(out)[i] = o;
  }
}

// ---- GEMM: C[M,N] = A[M,K] @ B[N,K]^T, bf16 in, fp32 acc ---------------
// BEST VERIFIED (round 8, reproduced rounds 15): m201-style 8-phase with
// barrier-crossing reads and per-phase counted VM(10). 266 us/GEMM,
// MfmaUtil ~45%, 0 bank conflicts, no spill.
//
// Per phase: {reads | 1 stage | [lgkm(8) if 12 reads]} -> BAR(mid) ->
//            LGKM(0) -> setprio(1) 16xMFMA setprio(0) -> VM(10) -> BAR.
//
// 256x256 tile, BK=64, 8 waves (2Mx4N), per-wave 128x64 = acc[8][4].
// LDS: 2 buf x 4 slots x [128x64] bf16 = 128 KiB; byte offsets:
// A0=+0, A1=+16384, B0=+32768, B1=+49152; buf1=+65536.
//
// Iter i = K-tiles 2i (buf0) / 2i+1 (buf1), 4 phases each.
// Reads: Ph1/5 a0q+bq0 (12), Ph2/6 bq1 (4), Ph3/7 a1q (8), Ph4/8 none.
// Stage stream: Ph1 A1(2i+1), Ph2 A0(2i+2), Ph3 B0(2i+2), Ph4 B1(2i+2),
//               Ph5 A1(2i+2), Ph6 A0(2i+3), Ph7 B0(2i+3), Ph8 B1(2i+3).
// Readiness ledger: each phase's read-halftile was staged 5 phases
// earlier with exactly 5 stages (10 gloads) issued after it -> VM(10)
// before the closing BAR of the PRECEDING phase guarantees it (vmcnt is
// per-wave; the barrier publishes "all waves' stages landed").
// Clobber ledger: every slot's restage is issued >=1 closing barrier
// after that slot's reads completed (reads complete at LGKM(0), before
// the same phase's closing BAR; restage is in a later phase).  All safe.
// Tail: last iteration peeled — only stage is Ph1's A1(nk-1); one VM(0)
// at Ph1-close drains everything; remaining tail phases need no VM.
// MFMA operands SWAPPED (mfma(b,a)): lane&15 = M-row, 4 acc regs = 4
// consecutive N-cols -> vectorized epilogue stores (verified r5-r15).
// EPI=0: bias+relu^2->bf16 (short4); EPI=1: bias->f32 (float4).

template <int EPI>
__global__ __launch_bounds__(512, 2) void gemm_bt(
    const short* __restrict__ A, const short* __restrict__ B,
    const float* __restrict__ bias, void* __restrict__ Cout,
    int M, int N, int K) {
  __shared__ __align__(16) short lds[2][4][128 * 64];

  const int tid  = threadIdx.x;
  const int wave = tid >> 6;
  const int lane = tid & 63;
  const int wr = wave >> 2;          // 0..1 -> M half (128 rows)
  const int wc = wave & 3;           // 0..3 -> N quarter (64 cols)
  const int fr = lane & 15, kq = lane >> 4;

  // T1: bijective XCD swizzle (nwg % 8 == 0), column-major in-chunk
  const int nwg = gridDim.x;
  const int w = (blockIdx.x & 7) * (nwg >> 3) + (blockIdx.x >> 3);
  const int gy = M >> 8;
  const int brow = w % gy;
  const int bcol = w / gy;

  f32x4 acc[8][4];
#pragma unroll
  for (int m = 0; m < 8; ++m)
#pragma unroll
    for (int n = 0; n < 4; ++n)
      acc[m][n] = (f32x4){0.f, 0.f, 0.f, 0.f};

  const int nk = K >> 6;             // K-tiles of 64 (even; nk>=4 here)

  // ---- T2 swizzle (within a 128x64 slot): granule g=r*8+gc stored at
  // P = g ^ (r&7). Verified 0 bank conflicts (rounds 2-16).
  const uint32_t LB = (uint32_t)(uintptr_t)&lds[0][0][0];
  uint32_t aA[4][2], aB[2][2];
#pragma unroll
  for (int m = 0; m < 4; ++m)
#pragma unroll
    for (int kk = 0; kk < 2; ++kk) {
      int r = wr * 64 + m * 16 + fr;
      int g = r * 8 + kk * 4 + kq;
      aA[m][kk] = LB + (uint32_t)((g ^ (r & 7)) * 16);
    }
#pragma unroll
  for (int n = 0; n < 2; ++n)
#pragma unroll
    for (int kk = 0; kk < 2; ++kk) {
      int r = wc * 32 + n * 16 + fr;
      int g = r * 8 + kk * 4 + kq;
      aB[n][kk] = LB + (uint32_t)((g ^ (r & 7)) * 16);
    }

  // ---- stage source addressing (inverse swizzle on global side)
  const int i0 = tid;
  const int gl0 = i0 ^ ((i0 >> 3) & 7);
  const int r0 = gl0 >> 3, c0 = gl0 & 7;
  const size_t rstep = (size_t)128 * K;

  const short* pA[2];
  const short* pB[2];
  {
    const int rb0 = (r0 >> 5) * 64 + (r0 & 31);
#pragma unroll
    for (int h = 0; h < 2; ++h) {
      pA[h] = A + (size_t)(brow * 256 + h * 64 + r0) * K + c0 * 8;
      pB[h] = B + (size_t)(bcol * 256 + rb0 + h * 32) * K + c0 * 8;
    }
  }

  const int dst0 = wave * 512, dst1 = 4096 + wave * 512;  // shorts in slot

#define STAGE(p, buf, slot)                              \
  do {                                                   \
    short* base_ = &lds[buf][slot][0];                   \
    gload_lds16((p), base_ + dst0);                      \
    gload_lds16((p) + rstep, base_ + dst1);              \
    (p) += 64;                                           \
  } while (0)

  // fragment regs + quadrant clusters (swapped operands)
  bf16x8 a0q[4][2], a1q[4][2], bq0[2][2], bq1[2][2];
  auto Q1 = [&]() {
#pragma unroll
    for (int m = 0; m < 4; ++m)
#pragma unroll
      for (int n = 0; n < 2; ++n)
#pragma unroll
        for (int kk = 0; kk < 2; ++kk)
          acc[m][n] = __builtin_amdgcn_mfma_f32_16x16x32_bf16(
              bq0[n][kk], a0q[m][kk], acc[m][n], 0, 0, 0);
  };
  auto Q2 = [&]() {
#pragma unroll
    for (int m = 0; m < 4; ++m)
#pragma unroll
      for (int n = 0; n < 2; ++n)
#pragma unroll
        for (int kk = 0; kk < 2; ++kk)
          acc[m][n + 2] = __builtin_amdgcn_mfma_f32_16x16x32_bf16(
              bq1[n][kk], a0q[m][kk], acc[m][n + 2], 0, 0, 0);
  };
  auto Q3 = [&]() {
#pragma unroll
    for (int m = 0; m < 4; ++m)
#pragma unroll
      for (int n = 0; n < 2; ++n)
#pragma unroll
        for (int kk = 0; kk < 2; ++kk)
          acc[m + 4][n + 2] = __builtin_amdgcn_mfma_f32_16x16x32_bf16(
              bq1[n][kk], a1q[m][kk], acc[m + 4][n + 2], 0, 0, 0);
  };
  auto Q4 = [&]() {
#pragma unroll
    for (int m = 0; m < 4; ++m)
#pragma unroll
      for (int n = 0; n < 2; ++n)
#pragma unroll
        for (int kk = 0; kk < 2; ++kk)
          acc[m + 4][n] = __builtin_amdgcn_mfma_f32_16x16x32_bf16(
              bq0[n][kk], a1q[m][kk], acc[m + 4][n], 0, 0, 0);
  };
  auto RD_A0 = [&](uint32_t cb) {
#pragma unroll
    for (int m = 0; m < 4; ++m)
#pragma unroll
      for (int kk = 0; kk < 2; ++kk)
        a0q[m][kk] = ds_readv(aA[m][kk] + cb);
  };
  auto RD_A1 = [&](uint32_t cb) {
#pragma unroll
    for (int m = 0; m < 4; ++m)
#pragma unroll
      for (int kk = 0; kk < 2; ++kk)
        a1q[m][kk] = ds_readv(aA[m][kk] + cb + 16384u);
  };
  auto RD_B0 = [&](uint32_t cb) {
#pragma unroll
    for (int n = 0; n < 2; ++n)
#pragma unroll
      for (int kk = 0; kk < 2; ++kk)
        bq0[n][kk] = ds_readv(aB[n][kk] + cb + 32768u);
  };
  auto RD_B1 = [&](uint32_t cb) {
#pragma unroll
    for (int n = 0; n < 2; ++n)
#pragma unroll
      for (int kk = 0; kk < 2; ++kk)
        bq1[n][kk] = ds_readv(aB[n][kk] + cb + 49152u);
  };

#define PRIO_ON  __builtin_amdgcn_s_setprio(1)
#define PRIO_OFF __builtin_amdgcn_s_setprio(0)

  // ---- prologue: tile0 full + tile1 {A0,B0,B1}; VM BEFORE BAR (publish).
  STAGE(pA[0], 0, 0);   // A0(0)
  STAGE(pB[0], 0, 2);   // B0(0)
  STAGE(pB[1], 0, 3);   // B1(0)
  STAGE(pA[1], 0, 1);   // A1(0)
  STAGE(pA[0], 1, 0);   // A0(1)
  STAGE(pB[0], 1, 2);   // B0(1)
  STAGE(pB[1], 1, 3);   // B1(1)
  VM(6);                // tile 0 (oldest 8) landed
  BAR();

  const int niter = nk >> 1;
  for (int i = 0; i < niter - 1; ++i) {
    // ============ K-tile 2i (buf0, cb=0) ============
    // Ph1
    RD_A0(0); RD_B0(0);
    STAGE(pA[1], 1, 1);                 // A1(2i+1)
    LGKM(8);
    BAR();
    LGKM(0);
    PRIO_ON; Q1(); PRIO_OFF;
    VM(10); BAR();
    // Ph2
    RD_B1(0);
    STAGE(pA[0], 0, 0);                 // A0(2i+2)
    BAR();
    LGKM(0);
    PRIO_ON; Q2(); PRIO_OFF;
    VM(10); BAR();
    // Ph3
    RD_A1(0);
    STAGE(pB[0], 0, 2);                 // B0(2i+2)
    BAR();
    LGKM(0);
    PRIO_ON; Q3(); PRIO_OFF;
    VM(10); BAR();
    // Ph4
    STAGE(pB[1], 0, 3);                 // B1(2i+2)
    BAR();
    PRIO_ON; Q4(); PRIO_OFF;
    VM(10); BAR();

    // ============ K-tile 2i+1 (buf1, cb=65536) ============
    // Ph5
    RD_A0(65536u); RD_B0(65536u);
    STAGE(pA[1], 0, 1);                 // A1(2i+2)
    LGKM(8);
    BAR();
    LGKM(0);
    PRIO_ON; Q1(); PRIO_OFF;
    VM(10); BAR();
    // Ph6
    RD_B1(65536u);
    STAGE(pA[0], 1, 0);                 // A0(2i+3)
    BAR();
    LGKM(0);
    PRIO_ON; Q2(); PRIO_OFF;
    VM(10); BAR();
    // Ph7
    RD_A1(65536u);
    STAGE(pB[0], 1, 2);                 // B0(2i+3)
    BAR();
    LGKM(0);
    PRIO_ON; Q3(); PRIO_OFF;
    VM(10); BAR();
    // Ph8
    STAGE(pB[1], 1, 3);                 // B1(2i+3)
    BAR();
    PRIO_ON; Q4(); PRIO_OFF;
    VM(10); BAR();
  }

  // ---- tail iteration (tiles nk-2 / nk-1): only stage = Ph1's A1(nk-1);
  // one VM(0) publish at Ph1-close, then drain-free phases.
  // Ph1
  RD_A0(0); RD_B0(0);
  STAGE(pA[1], 1, 1);                   // A1(nk-1)
  LGKM(8);
  BAR();
  LGKM(0);
  PRIO_ON; Q1(); PRIO_OFF;
  VM(0); BAR();                          // everything landed
  // Ph2
  RD_B1(0); BAR(); LGKM(0);
  PRIO_ON; Q2(); PRIO_OFF; BAR();
  // Ph3
  RD_A1(0); BAR(); LGKM(0);
  PRIO_ON; Q3(); PRIO_OFF; BAR();
  // Ph4
  PRIO_ON; Q4(); PRIO_OFF;
  BAR();
  // Ph5
  RD_A0(65536u); RD_B0(65536u); BAR(); LGKM(0);
  PRIO_ON; Q1(); PRIO_OFF; BAR();
  // Ph6
  RD_B1(65536u); BAR(); LGKM(0);
  PRIO_ON; Q2(); PRIO_OFF; BAR();
  // Ph7
  RD_A1(65536u); BAR(); LGKM(0);
  PRIO_ON; Q3(); PRIO_OFF; BAR();
  // Ph8
  PRIO_ON; Q4(); PRIO_OFF;

  // ---- epilogue (swapped-operand layout, verified r5-r15): row=m*16+fr,
  // cols = n*16 + q*4 + {0..3} -> 4-wide stores.
  const int q = lane >> 4;
  if (EPI == 0) {
    short* C = (short*)Cout;
#pragma unroll
    for (int m = 0; m < 8; ++m) {
      const int row = brow * 256 + wr * 128 + m * 16 + fr;
#pragma unroll
      for (int n = 0; n < 4; ++n) {
        const int col = bcol * 256 + wc * 64 + n * 16 + q * 4;
        const float4 bv = *(const float4*)&bias[col];
        short4 o;
        float v0 = acc[m][n][0] + bv.x; v0 = v0 > 0.f ? v0 * v0 : 0.f;
        float v1 = acc[m][n][1] + bv.y; v1 = v1 > 0.f ? v1 * v1 : 0.f;
        float v2 = acc[m][n][2] + bv.z; v2 = v2 > 0.f ? v2 * v2 : 0.f;
        float v3 = acc[m][n][3] + bv.w; v3 = v3 > 0.f ? v3 * v3 : 0.f;
        o.x = f2bf(v0); o.y = f2bf(v1); o.z = f2bf(v2); o.w = f2bf(v3);
        *(short4*)&C[(size_t)row * N + col] = o;
      }
    }
  } else {
    float* C = (float*)Cout;
#pragma unroll
    for (int m = 0; m < 8; ++m) {
      const int row = brow * 256 + wr * 128 + m * 16 + fr;
#pragma unroll
      for (int n = 0; n < 4; ++n) {
        const int col = bcol * 256 + wc * 64 + n * 16 + q * 4;
        const float4 bv = *(const float4*)&bias[col];
        float4 o;
        o.x = acc[m][n][0] + bv.x;
        o.y = acc[m][n][1] + bv.y;
        o.z = acc[m][n][2] + bv.z;
        o.w = acc[m][n][3] + bv.w;
        *(float4*)&C[(size_t)row * N + col] = o;
      }
    }
  }
#undef STAGE
}

// ---- launch -------------------------------------------------------------

extern "C" void kernel_launch(void* const* d_in, const int* in_sizes, int n_in,
                              void* d_out, int out_size, void* d_ws,
                              size_t ws_size, hipStream_t stream) {
  const float* x  = (const float*)d_in[0];
  const float* w1 = (const float*)d_in[1];
  const float* b1 = (const float*)d_in[2];
  const float* w2 = (const float*)d_in[3];
  const float* b2 = (const float*)d_in[4];
  float* out = (float*)d_out;

  const int H = in_sizes[2];            // 8192
  const int D = in_sizes[4];            // 2048
  const int M = in_sizes[0] / D;        // B*S = 8192

  short* xb  = (short*)d_ws;                 // M*D
  short* w1b = xb  + (size_t)M * D;          // H*D
  short* w2b = w1b + (size_t)H * D;          // D*H
  short* act = w2b + (size_t)D * H;          // M*H

  {
    int n4 = (M * D) / 4;
    cvt_f32_bf16<<<(n4 + 255) / 256, 256, 0, stream>>>(x, xb, n4);
    n4 = (H * D) / 4;
    cvt_f32_bf16<<<(n4 + 255) / 256, 256, 0, stream>>>(w1, w1b, n4);
    n4 = (D * H) / 4;
    cvt_f32_bf16<<<(n4 + 255) / 256, 256, 0, stream>>>(w2, w2b, n4);
  }

  // GEMM1: [M,D] @ [H,D]^T -> sqrelu -> act[M,H] (bf16)
  gemm_bt<0><<<(M / 256) * (H / 256), 512, 0, stream>>>(
      xb, w1b, b1, (void*)act, M, H, D);
  // GEMM2: [M,H] @ [D,H]^T -> + b2 -> out[M,D] (f32)
  gemm_bt<1><<<(M / 256) * (D / 256), 512, 0, stream>>>(
      act, w2b, b2, (void*)out, M, D, H);
}